// Round 3
// baseline (48.778 us; speedup 1.0000x reference)
//
#include <hip/hip_runtime.h>
#include <hip/hip_bf16.h>

// out[d,t] = (sum_j exp(s[t,j]) * u[j,d]) / (sum_j exp(s[t,j]))
// Fused exp-GEMM (ones-column in B gives the denominator from the same MFMAs).
// R3 change: sched_barrier(0) fences pin the depth-4 rotating s-prefetch into
// its issuing iteration — R2's buffer was silently sunk by the scheduler
// (VGPR=56 proved it). launch_bounds(256,3) caps regalloc at ~168 VGPR.

constexpr int T_DIM = 65536;
constexpr int J_DIM = 512;
constexpr int D_DIM = 128;
constexpr int KK_STEPS = J_DIM / 32;   // 16
constexpr int NFRAG = 9;               // 8 N-fragments for D=128 + 1 ones-column
constexpr int PF_DEPTH = 4;            // s-load prefetch depth (iterations)

typedef __attribute__((ext_vector_type(4))) float  f32x4;
typedef __attribute__((ext_vector_type(8))) short  s16x8;
typedef __attribute__((ext_vector_type(8))) __bf16 bf16x8;

__device__ __forceinline__ short f2bf_rne(float f) {
    unsigned u = __builtin_bit_cast(unsigned, f);
    u += 0x7fffu + ((u >> 16) & 1u);   // round-to-nearest-even
    return (short)(u >> 16);
}

__global__ __launch_bounds__(256) void prep_b(const float* __restrict__ u,
                                              short* __restrict__ bp) {
    int tid = blockIdx.x * blockDim.x + threadIdx.x;
    if (tid >= KK_STEPS * NFRAG * 64) return;
    int l  = tid & 63;
    int nf = (tid >> 6) % NFRAG;
    int kk = tid / (64 * NFRAG);
    int d  = nf * 16 + (l & 15);
    int k0 = kk * 32 + 8 * (l >> 4);
    s16x8 o;
#pragma unroll
    for (int i = 0; i < 8; ++i) {
        float v = (nf < 8) ? u[(size_t)(k0 + i) * D_DIM + d]
                           : (((l & 15) == 0) ? 1.0f : 0.0f);
        o[i] = f2bf_rne(v);
    }
    *reinterpret_cast<s16x8*>(bp + (size_t)tid * 8) = o;
}

__global__ __launch_bounds__(256, 3) void c2q_main(const float* __restrict__ sm,
                                                   const short* __restrict__ bp,
                                                   float* __restrict__ out) {
    const int tid  = threadIdx.x;
    const int l    = tid & 63;
    const int w    = tid >> 6;        // wave 0..3
    const int lmod = l & 15;
    const int lh   = l >> 4;          // 0..3
    const int r0   = blockIdx.x * 64 + w * 16;   // this wave's first t-row

    // A fragment loads straight from global: lane holds row r0+lmod,
    // k = kk*32 + 8*lh + i  -> 8 contiguous floats (32B) per lane per step.
    const float* sp = sm + (size_t)(r0 + lmod) * J_DIM + lh * 8;
    const short* bl = bp + l * 8;

    f32x4 acc[NFRAG];
#pragma unroll
    for (int nf = 0; nf < NFRAG; ++nf) acc[nf] = (f32x4){0.f, 0.f, 0.f, 0.f};

    // ---- depth-4 rotating prefetch buffer, pinned by sched_barrier fences ----
    f32x4 sbuf[PF_DEPTH][2];
#pragma unroll
    for (int p = 0; p < PF_DEPTH; ++p) {
        sbuf[p][0] = *reinterpret_cast<const f32x4*>(sp + p * 32);
        sbuf[p][1] = *reinterpret_cast<const f32x4*>(sp + p * 32 + 4);
    }
    __builtin_amdgcn_sched_barrier(0);   // prologue loads may not sink

#pragma unroll
    for (int kk = 0; kk < KK_STEPS; ++kk) {
        f32x4 s0 = sbuf[kk & (PF_DEPTH - 1)][0];
        f32x4 s1 = sbuf[kk & (PF_DEPTH - 1)][1];
        // re-issue this slot for iteration kk+PF_DEPTH (static after unroll)
        if (kk + PF_DEPTH < KK_STEPS) {
            sbuf[kk & (PF_DEPTH - 1)][0] =
                *reinterpret_cast<const f32x4*>(sp + (kk + PF_DEPTH) * 32);
            sbuf[kk & (PF_DEPTH - 1)][1] =
                *reinterpret_cast<const f32x4*>(sp + (kk + PF_DEPTH) * 32 + 4);
        }
        s16x8 a;
        a[0] = f2bf_rne(__expf(s0[0]));
        a[1] = f2bf_rne(__expf(s0[1]));
        a[2] = f2bf_rne(__expf(s0[2]));
        a[3] = f2bf_rne(__expf(s0[3]));
        a[4] = f2bf_rne(__expf(s1[0]));
        a[5] = f2bf_rne(__expf(s1[1]));
        a[6] = f2bf_rne(__expf(s1[2]));
        a[7] = f2bf_rne(__expf(s1[3]));
        bf16x8 av = __builtin_bit_cast(bf16x8, a);
        const short* bk = bl + kk * (NFRAG * 64 * 8);
#pragma unroll
        for (int nf = 0; nf < NFRAG; ++nf) {
            bf16x8 bv = __builtin_bit_cast(bf16x8,
                *reinterpret_cast<const s16x8*>(bk + nf * 512));
            acc[nf] = __builtin_amdgcn_mfma_f32_16x16x32_bf16(av, bv, acc[nf], 0, 0, 0);
        }
        __builtin_amdgcn_sched_barrier(0);   // iteration fence: no cross-motion
    }

    // Denominator lives in acc[8] (ones-column -> col 0 of that fragment),
    // reg r corresponds to t-row r0 + 4*lh + r. Broadcast within 16-lane group.
    float inv[4];
#pragma unroll
    for (int r = 0; r < 4; ++r) {
        float den = __shfl(acc[8][r], (l & 48), 64);
        inv[r] = 1.0f / den;
    }

    // C/D layout: col = lane&15 (-> d), row = 4*(lane>>4)+reg (-> t).
#pragma unroll
    for (int nf = 0; nf < 8; ++nf) {
        f32x4 v;
#pragma unroll
        for (int r = 0; r < 4; ++r) v[r] = acc[nf][r] * inv[r];
        *reinterpret_cast<f32x4*>(out + (size_t)(nf * 16 + lmod) * T_DIM
                                  + r0 + 4 * lh) = v;
    }
}

extern "C" void kernel_launch(void* const* d_in, const int* in_sizes, int n_in,
                              void* d_out, int out_size, void* d_ws, size_t ws_size,
                              hipStream_t stream) {
    const float* u = (const float*)d_in[0];   // (1, 512, 128) fp32
    const float* s = (const float*)d_in[1];   // (65536, 512) fp32
    float* out = (float*)d_out;               // (128, 65536) fp32
    short* bp = (short*)d_ws;                 // 147456 bytes used

    prep_b<<<(KK_STEPS * NFRAG * 64 + 255) / 256, 256, 0, stream>>>(u, bp);
    c2q_main<<<T_DIM / 64, 256, 0, stream>>>(s, bp, out);
}

// Round 4
// 40.557 us; speedup vs baseline: 1.2027x; 1.2027x over previous
//
#include <hip/hip_runtime.h>
#include <hip/hip_bf16.h>

// out[d,t] = (sum_j exp(s[t,j]) * u[j,d]) / (sum_j exp(s[t,j]))
// Fused exp-GEMM. R4 change: B fragments live in LDS, loaded ONCE per block
// (was: every wave re-read 144KB of B from L2 per K-pass = ~590MB through the
// vector-memory path — the hidden serializer). Denominator now computed on the
// VALU (8 adds/iter + shfl_xor reduce), dropping the ones-column so B fits in
// 128KB LDS. K-loop VMEM is only the depth-4 s-prefetch: counted vmcnt, never
// drained by B reads (ds_read_b128 / lgkm domain).

constexpr int T_DIM = 65536;
constexpr int J_DIM = 512;
constexpr int D_DIM = 128;
constexpr int KK_STEPS = J_DIM / 32;   // 16
constexpr int NFRAG = 8;               // 8 N-fragments covering D=128
constexpr int PF_DEPTH = 4;            // s-load prefetch depth (iterations)
constexpr int BP_ELEMS = KK_STEPS * NFRAG * 64;   // s16x8 elements = 8192 (128KB)

typedef __attribute__((ext_vector_type(4))) float  f32x4;
typedef __attribute__((ext_vector_type(8))) short  s16x8;
typedef __attribute__((ext_vector_type(8))) __bf16 bf16x8;

__device__ __forceinline__ short f2bf_rne(float f) {
    unsigned u = __builtin_bit_cast(unsigned, f);
    u += 0x7fffu + ((u >> 16) & 1u);   // round-to-nearest-even
    return (short)(u >> 16);
}

__global__ __launch_bounds__(256) void prep_b(const float* __restrict__ u,
                                              short* __restrict__ bp) {
    int tid = blockIdx.x * blockDim.x + threadIdx.x;
    if (tid >= BP_ELEMS) return;
    int l  = tid & 63;
    int nf = (tid >> 6) & (NFRAG - 1);
    int kk = tid >> 9;
    int d  = nf * 16 + (l & 15);
    int k0 = kk * 32 + 8 * (l >> 4);
    s16x8 o;
#pragma unroll
    for (int i = 0; i < 8; ++i)
        o[i] = f2bf_rne(u[(size_t)(k0 + i) * D_DIM + d]);
    *reinterpret_cast<s16x8*>(bp + (size_t)tid * 8) = o;
}

__global__ __launch_bounds__(512, 2) void c2q_main(const float* __restrict__ sm,
                                                   const short* __restrict__ bp,
                                                   float* __restrict__ out) {
    __shared__ s16x8 bsh[BP_ELEMS];    // [kk][nf][lane] — 131072 bytes

    const int tid  = threadIdx.x;
    const int l    = tid & 63;
    const int w    = tid >> 6;        // wave 0..7
    const int lmod = l & 15;
    const int lh   = l >> 4;          // 0..3
    const int r0   = blockIdx.x * 128 + w * 16;  // this wave's first t-row

    // A-fragment source: lane holds row r0+lmod, k = kk*32 + 8*lh + i.
    const float* sp = sm + (size_t)(r0 + lmod) * J_DIM + lh * 8;

    // ---- s-prefetch prologue (issue before the LDS fill so HBM overlaps) ----
    f32x4 sbuf[PF_DEPTH][2];
#pragma unroll
    for (int p = 0; p < PF_DEPTH; ++p) {
        sbuf[p][0] = *reinterpret_cast<const f32x4*>(sp + p * 32);
        sbuf[p][1] = *reinterpret_cast<const f32x4*>(sp + p * 32 + 4);
    }

    // ---- one-time B fill: 512 threads x 16 iters x 16B (reg-staged) ----
    {
        const s16x8* bps = reinterpret_cast<const s16x8*>(bp);
#pragma unroll
        for (int it = 0; it < BP_ELEMS / 512; ++it)
            bsh[it * 512 + tid] = bps[it * 512 + tid];
    }
    __syncthreads();

    f32x4 acc[NFRAG];
#pragma unroll
    for (int nf = 0; nf < NFRAG; ++nf) acc[nf] = (f32x4){0.f, 0.f, 0.f, 0.f};
    float den = 0.f;

#pragma unroll
    for (int kk = 0; kk < KK_STEPS; ++kk) {
        f32x4 s0 = sbuf[kk & (PF_DEPTH - 1)][0];
        f32x4 s1 = sbuf[kk & (PF_DEPTH - 1)][1];
        if (kk + PF_DEPTH < KK_STEPS) {
            sbuf[kk & (PF_DEPTH - 1)][0] =
                *reinterpret_cast<const f32x4*>(sp + (kk + PF_DEPTH) * 32);
            sbuf[kk & (PF_DEPTH - 1)][1] =
                *reinterpret_cast<const f32x4*>(sp + (kk + PF_DEPTH) * 32 + 4);
        }
        float e0 = __expf(s0[0]), e1 = __expf(s0[1]);
        float e2 = __expf(s0[2]), e3 = __expf(s0[3]);
        float e4 = __expf(s1[0]), e5 = __expf(s1[1]);
        float e6 = __expf(s1[2]), e7 = __expf(s1[3]);
        den += ((e0 + e1) + (e2 + e3)) + ((e4 + e5) + (e6 + e7));
        s16x8 a;
        a[0] = f2bf_rne(e0); a[1] = f2bf_rne(e1);
        a[2] = f2bf_rne(e2); a[3] = f2bf_rne(e3);
        a[4] = f2bf_rne(e4); a[5] = f2bf_rne(e5);
        a[6] = f2bf_rne(e6); a[7] = f2bf_rne(e7);
        bf16x8 av = __builtin_bit_cast(bf16x8, a);
#pragma unroll
        for (int nf = 0; nf < NFRAG; ++nf) {
            bf16x8 bv = __builtin_bit_cast(bf16x8, bsh[(kk * NFRAG + nf) * 64 + l]);
            acc[nf] = __builtin_amdgcn_mfma_f32_16x16x32_bf16(av, bv, acc[nf], 0, 0, 0);
        }
        __builtin_amdgcn_sched_barrier(0);   // keep per-iteration structure
    }

    // den(l) currently holds row lmod's partial over k-chunk lh: reduce chunks.
    den += __shfl_xor(den, 16, 64);
    den += __shfl_xor(den, 32, 64);
    // C/D layout: col = lane&15 (-> d), row = 4*(lane>>4)+reg (-> t).
    // Row m's denominator lives in lanes with (lane&15)==m; lane m qualifies.
    float inv[4];
#pragma unroll
    for (int r = 0; r < 4; ++r)
        inv[r] = 1.0f / __shfl(den, 4 * lh + r, 64);

#pragma unroll
    for (int nf = 0; nf < NFRAG; ++nf) {
        f32x4 v;
#pragma unroll
        for (int r = 0; r < 4; ++r) v[r] = acc[nf][r] * inv[r];
        *reinterpret_cast<f32x4*>(out + (size_t)(nf * 16 + lmod) * T_DIM
                                  + r0 + 4 * lh) = v;
    }
}

extern "C" void kernel_launch(void* const* d_in, const int* in_sizes, int n_in,
                              void* d_out, int out_size, void* d_ws, size_t ws_size,
                              hipStream_t stream) {
    const float* u = (const float*)d_in[0];   // (1, 512, 128) fp32
    const float* s = (const float*)d_in[1];   // (65536, 512) fp32
    float* out = (float*)d_out;               // (128, 65536) fp32
    short* bp = (short*)d_ws;                 // 131072 bytes used

    prep_b<<<(BP_ELEMS + 255) / 256, 256, 0, stream>>>(u, bp);
    c2q_main<<<T_DIM / 128, 512, 0, stream>>>(s, bp, out);
}